// Round 2
// baseline (612.519 us; speedup 1.0000x reference)
//
#include <hip/hip_runtime.h>

#define S_LEN 4096
#define DIM 64
#define NHEAD 64        // B*H = 4*16
#define NCHUNK 8
#define CHUNK (S_LEN / NCHUNK)   // 512 s-rows per block
#define SW (CHUNK / 4)           // 128 s-rows per wave
#define PHEAD 4160      // 65*64 floats per head: rows e=0..63 are KV^T, row 64 = Ksum

__device__ __forceinline__ float elu1(float x) {
    // elu(x)+1 : x>0 -> x+1 ; x<=0 -> exp(x)
    return x > 0.0f ? x + 1.0f : __expf(x);
}

// ---------------- pass 1: partial KV^T (64x64) + Ksum per (head, chunk) ----------------
// No LDS in the main loop: each wave owns a private 128-row s-range, 8x8 register
// tile per lane, K/V rows read directly from global (broadcast addresses -> one
// cacheline fetch per row). Waves combine via LDS atomicAdd in the epilogue.
__global__ __launch_bounds__(256, 4) void pass1_kv(
    const float* __restrict__ K, const float* __restrict__ V,
    const float* __restrict__ mask, float* __restrict__ partials)
{
    const int head  = blockIdx.x >> 3;
    const int chunk = blockIdx.x & 7;
    const int t    = threadIdx.x;
    const int lane = t & 63;
    const int wave = t >> 6;
    const int tx = lane & 7;      // e-group: e = tx*8 + j
    const int ty = lane >> 3;     // d-group: d = ty*8 + i

    __shared__ float sm[65 * 65];   // sm[e*65 + d], row 64 = ksum (stride 65 breaks bank alignment)
    for (int i = t; i < 65 * 65; i += 256) sm[i] = 0.f;

    float acc[8][8] = {};
    float ks[8] = {};

    const long hbase = (long)head * S_LEN * DIM;
    const int  s0    = chunk * CHUNK + wave * SW;
    const float* kp = K + hbase + (long)s0 * DIM + ty * 8;
    const float* vp = V + hbase + (long)s0 * DIM + tx * 8;
    const float* mp = mask + head * S_LEN + s0;

    #pragma unroll 2
    for (int s = 0; s < SW; ++s) {
        const float4 ka = *(const float4*)(kp + s * DIM);
        const float4 kb = *(const float4*)(kp + s * DIM + 4);
        const float4 va = *(const float4*)(vp + s * DIM);
        const float4 vb = *(const float4*)(vp + s * DIM + 4);
        const float m = mp[s];
        float kk[8], vv[8];
        kk[0] = elu1(ka.x) * m; kk[1] = elu1(ka.y) * m; kk[2] = elu1(ka.z) * m; kk[3] = elu1(ka.w) * m;
        kk[4] = elu1(kb.x) * m; kk[5] = elu1(kb.y) * m; kk[6] = elu1(kb.z) * m; kk[7] = elu1(kb.w) * m;
        vv[0] = va.x; vv[1] = va.y; vv[2] = va.z; vv[3] = va.w;
        vv[4] = vb.x; vv[5] = vb.y; vv[6] = vb.z; vv[7] = vb.w;
        #pragma unroll
        for (int i = 0; i < 8; ++i) {
            #pragma unroll
            for (int j = 0; j < 8; ++j) acc[i][j] += kk[i] * vv[j];
            ks[i] += kk[i];
        }
    }

    __syncthreads();   // zeros visible to all before atomics
    // scatter-add with lane-rotated order to spread banks
    #pragma unroll
    for (int jj = 0; jj < 8; ++jj) {
        const int j = (jj + tx) & 7;
        #pragma unroll
        for (int ii = 0; ii < 8; ++ii) {
            const int i = (ii + ty) & 7;
            atomicAdd(&sm[(tx * 8 + j) * 65 + ty * 8 + i], acc[i][j]);
        }
    }
    if (tx == 0) {    // ks is duplicated across the 8 tx lanes; add once
        #pragma unroll
        for (int i = 0; i < 8; ++i) atomicAdd(&sm[64 * 65 + ty * 8 + i], ks[i]);
    }
    __syncthreads();

    float* P = partials + (long)(head * NCHUNK + chunk) * PHEAD;
    for (int idx = t; idx < PHEAD; idx += 256) {
        const int e = idx >> 6, d = idx & 63;
        P[idx] = sm[e * 65 + d];
    }
}

// ---------------- reduce: sum NCHUNK partials -> final KV^T (+Ksum) per head ----------------
__global__ __launch_bounds__(256) void reduce_kv(
    const float* __restrict__ partials, float* __restrict__ kvf)
{
    const int head = blockIdx.x;
    for (int idx = threadIdx.x; idx < PHEAD; idx += 256) {
        float s = 0.f;
        #pragma unroll
        for (int c = 0; c < NCHUNK; ++c)
            s += partials[(long)(head * NCHUNK + c) * PHEAD + idx];
        kvf[(long)head * PHEAD + idx] = s;
    }
}

// ---------------- pass 2: out = (Qf @ KV) / (Qf . Ksum) ----------------
// Lane-per-row, no LDS. KV^T addressing is fully uniform (blockIdx + loop
// constants only) -> compiler scalarizes to s_load; inner loop is v_fma with
// one SGPR operand. One column at a time keeps live SGPRs at 64.
__global__ __launch_bounds__(256, 4) void pass2_out(
    const float* __restrict__ Q, const float* __restrict__ kvf,
    float* __restrict__ out)
{
    const int head = blockIdx.x >> 4;
    const int tile = blockIdx.x & 15;
    const int t    = threadIdx.x;
    const int lane = t & 63;
    const int wave = t >> 6;
    const int row  = tile * 256 + wave * 64 + lane;

    const long hbase = (long)head * S_LEN * DIM;
    const float* qp = Q + hbase + (long)row * DIM;

    float q[64];
    #pragma unroll
    for (int i = 0; i < 16; ++i) {
        const float4 v = *(const float4*)(qp + i * 4);
        q[i * 4 + 0] = elu1(v.x); q[i * 4 + 1] = elu1(v.y);
        q[i * 4 + 2] = elu1(v.z); q[i * 4 + 3] = elu1(v.w);
    }

    const float* __restrict__ kvt = kvf + (long)head * PHEAD;

    float denom = 0.f;
    #pragma unroll
    for (int d = 0; d < 64; ++d) denom += q[d] * kvt[64 * 64 + d];
    const float rz = 1.0f / denom;

    float* op = out + hbase + (long)row * DIM;
    for (int eg = 0; eg < 16; ++eg) {
        float r[4];
        #pragma unroll
        for (int j = 0; j < 4; ++j) {
            const float* kr = kvt + (eg * 4 + j) * 64;
            float a = 0.f;
            #pragma unroll
            for (int d = 0; d < 64; ++d) a += q[d] * kr[d];
            r[j] = a * rz;
        }
        *(float4*)(op + eg * 4) = make_float4(r[0], r[1], r[2], r[3]);
    }
}

extern "C" void kernel_launch(void* const* d_in, const int* in_sizes, int n_in,
                              void* d_out, int out_size, void* d_ws, size_t ws_size,
                              hipStream_t stream) {
    const float* Q    = (const float*)d_in[0];
    const float* K    = (const float*)d_in[1];
    const float* V    = (const float*)d_in[2];
    const float* mask = (const float*)d_in[3];
    float* out = (float*)d_out;

    float* partials = (float*)d_ws;                           // 64*8*4160 floats ≈ 8.5 MB
    float* kvf = partials + (long)NHEAD * NCHUNK * PHEAD;     // 64*4160 floats ≈ 1.1 MB

    pass1_kv<<<NHEAD * NCHUNK, 256, 0, stream>>>(K, V, mask, partials);
    reduce_kv<<<NHEAD, 256, 0, stream>>>(partials, kvf);
    pass2_out<<<NHEAD * 16, 256, 0, stream>>>(Q, kvf, out);
}

// Round 3
// 594.327 us; speedup vs baseline: 1.0306x; 1.0306x over previous
//
#include <hip/hip_runtime.h>

#define S_LEN 4096
#define DIM 64
#define NHEAD 64        // B*H = 4*16
#define NCHUNK 8
#define CHUNK (S_LEN / NCHUNK)   // 512 s-rows per block
#define PHEAD 4160      // 65*64 floats per head: 0..4095 KV (layout varies), 4096.. = Ksum

__device__ __forceinline__ float elu1(float x) {
    // elu(x)+1 : x>0 -> x+1 ; x<=0 -> exp(x)
    return x > 0.0f ? x + 1.0f : __expf(x);
}

// ---------------- pass 1: partial KV^T (64x64) + Ksum per (head, chunk) ----------------
// 1024 threads = 16 waves; each wave owns a private 32-row s-range, 8x8 register
// tile per lane, K/V read directly from global (broadcast addresses). Waves
// combine via rotated LDS atomicAdd in the epilogue. 16 waves/CU resident.
__global__ __launch_bounds__(1024) void pass1_kv(
    const float* __restrict__ K, const float* __restrict__ V,
    const float* __restrict__ mask, float* __restrict__ partials)
{
    const int head  = blockIdx.x >> 3;
    const int chunk = blockIdx.x & 7;
    const int t    = threadIdx.x;
    const int lane = t & 63;
    const int wave = t >> 6;      // 0..15
    const int tx = lane & 7;      // e-group: e = tx*8 + j
    const int ty = lane >> 3;     // d-group: d = ty*8 + i

    __shared__ float sm[65 * 65];   // sm[e*65 + d], row 64 = ksum
    for (int i = t; i < 65 * 65; i += 1024) sm[i] = 0.f;
    __syncthreads();   // zeros visible before any atomics

    float acc[8][8] = {};
    float ks[8] = {};

    const long hbase = (long)head * S_LEN * DIM;
    const int  s0    = chunk * CHUNK + wave * 32;
    const float* kp = K + hbase + (long)s0 * DIM + ty * 8;
    const float* vp = V + hbase + (long)s0 * DIM + tx * 8;
    const float* mp = mask + head * S_LEN + s0;

    #pragma unroll 2
    for (int s = 0; s < 32; ++s) {
        const float4 ka = *(const float4*)(kp + s * DIM);
        const float4 kb = *(const float4*)(kp + s * DIM + 4);
        const float4 va = *(const float4*)(vp + s * DIM);
        const float4 vb = *(const float4*)(vp + s * DIM + 4);
        const float m = mp[s];
        float kk[8], vv[8];
        kk[0] = elu1(ka.x) * m; kk[1] = elu1(ka.y) * m; kk[2] = elu1(ka.z) * m; kk[3] = elu1(ka.w) * m;
        kk[4] = elu1(kb.x) * m; kk[5] = elu1(kb.y) * m; kk[6] = elu1(kb.z) * m; kk[7] = elu1(kb.w) * m;
        vv[0] = va.x; vv[1] = va.y; vv[2] = va.z; vv[3] = va.w;
        vv[4] = vb.x; vv[5] = vb.y; vv[6] = vb.z; vv[7] = vb.w;
        #pragma unroll
        for (int i = 0; i < 8; ++i) {
            #pragma unroll
            for (int j = 0; j < 8; ++j) acc[i][j] += kk[i] * vv[j];
            ks[i] += kk[i];
        }
    }

    // combine 16 waves: rotated scatter-add (wave-dependent order decorrelates banks)
    #pragma unroll
    for (int jj = 0; jj < 8; ++jj) {
        const int j = (jj + tx + wave) & 7;
        #pragma unroll
        for (int ii = 0; ii < 8; ++ii) {
            const int i = (ii + ty + wave) & 7;
            atomicAdd(&sm[(tx * 8 + j) * 65 + ty * 8 + i], acc[i][j]);
        }
    }
    if (tx == 0) {    // ks duplicated across the 8 tx lanes; add once per wave
        #pragma unroll
        for (int i = 0; i < 8; ++i) atomicAdd(&sm[64 * 65 + ty * 8 + i], ks[i]);
    }
    __syncthreads();

    // store partial (e-major): P[e*64+d], P[4096+d] = ksum
    float* P = partials + (long)(head * NCHUNK + chunk) * PHEAD;
    for (int idx = t; idx < PHEAD; idx += 1024) {
        const int e = idx >> 6, d = idx & 63;
        P[idx] = sm[e * 65 + d];
    }
}

// ---------------- reduce: sum NCHUNK partials; transpose main part to d-major ----------------
// output kvf[head]: [d*64+e] for d,e<64 ; [4096+d] = Ksum[d]
__global__ __launch_bounds__(256) void reduce_kv(
    const float* __restrict__ partials, float* __restrict__ kvf)
{
    const int head = blockIdx.x >> 2;
    const int part = blockIdx.x & 3;
    for (int idx = part * 1040 + threadIdx.x; idx < (part + 1) * 1040; idx += 256) {
        float s = 0.f;
        #pragma unroll
        for (int c = 0; c < NCHUNK; ++c)
            s += partials[(long)(head * NCHUNK + c) * PHEAD + idx];
        int pos;
        if (idx < 4096) { const int e = idx >> 6, d = idx & 63; pos = d * 64 + e; }
        else            { pos = idx; }
        kvf[(long)head * PHEAD + pos] = s;
    }
}

// ---------------- pass 2: out = (Qf @ KV) * (1 / (Qf . Ksum)) ----------------
// Block = 256 thr (4 waves), out tile 256 rows x 64 cols, 8x8 per lane.
// qT[d][r] transposed in LDS with row-rotation swizzle; kvd[d][e] + ksum staged once.
#define LQ 260     // qT row stride (floats); rotation keeps banks 2-way
#define LKV 68
__device__ __forceinline__ int rotq(int r, int c) { return (r + 4 * (c >> 2)) & 255; }

__global__ __launch_bounds__(256) void pass2_out(
    const float* __restrict__ Q, const float* __restrict__ kvf,
    float* __restrict__ out)
{
    const int head = blockIdx.x >> 4;
    const int tile = blockIdx.x & 15;
    const int t    = threadIdx.x;
    const int lane = t & 63;
    const int wave = t >> 6;
    const int rbase = tile * 256;

    __shared__ float qT[64 * LQ];      // 66.6 KB
    __shared__ float kvd[64 * LKV];    // 17.4 KB
    __shared__ float ksum[64];

    const long hbase = (long)head * S_LEN * DIM;
    const float* kvsrc = kvf + (long)head * PHEAD;

    // stage KV (d-major straight copy) + ksum
    #pragma unroll
    for (int i = 0; i < 4; ++i) {
        const int v = i * 256 + t;
        const int d = v >> 4, e0 = (v & 15) * 4;
        *(float4*)&kvd[d * LKV + e0] = *(const float4*)(kvsrc + d * 64 + e0);
    }
    if (t < 16) *(float4*)&ksum[t * 4] = *(const float4*)(kvsrc + 4096 + t * 4);

    // stage Q transposed with elu+1, rotation swizzle
    #pragma unroll
    for (int i = 0; i < 16; ++i) {
        const int v = i * 256 + t;
        const int r = v >> 4, c0 = (v & 15) * 4;
        const float4 qv = *(const float4*)(Q + hbase + (long)(rbase + r) * DIM + c0);
        float q4[4] = { elu1(qv.x), elu1(qv.y), elu1(qv.z), elu1(qv.w) };
        #pragma unroll
        for (int j = 0; j < 4; ++j)
            qT[(c0 + j) * LQ + rotq(r, c0 + j)] = q4[j];
    }
    __syncthreads();

    const int rg = lane >> 3;        // row group: rows r0..r0+7
    const int eg = lane & 7;         // col group: e = eg*8..+7
    const int r0 = wave * 64 + rg * 8;

    float acc[8][8] = {};
    float dn[8] = {};

    for (int d = 0; d < 64; ++d) {
        const int sh = 4 * (d >> 2);
        const float4 qa = *(const float4*)&qT[d * LQ + ((r0 + sh) & 255)];
        const float4 qb = *(const float4*)&qT[d * LQ + ((r0 + 4 + sh) & 255)];
        const float4 ka = *(const float4*)&kvd[d * LKV + eg * 8];
        const float4 kb = *(const float4*)&kvd[d * LKV + eg * 8 + 4];
        const float ksd = ksum[d];
        float qv[8] = { qa.x, qa.y, qa.z, qa.w, qb.x, qb.y, qb.z, qb.w };
        float kv[8] = { ka.x, ka.y, ka.z, ka.w, kb.x, kb.y, kb.z, kb.w };
        #pragma unroll
        for (int i = 0; i < 8; ++i) {
            #pragma unroll
            for (int j = 0; j < 8; ++j) acc[i][j] += qv[i] * kv[j];
            dn[i] += qv[i] * ksd;
        }
    }

    #pragma unroll
    for (int i = 0; i < 8; ++i) {
        const float rz = 1.0f / dn[i];
        const long rowoff = hbase + (long)(rbase + r0 + i) * DIM + eg * 8;
        *(float4*)(out + rowoff)     = make_float4(acc[i][0] * rz, acc[i][1] * rz, acc[i][2] * rz, acc[i][3] * rz);
        *(float4*)(out + rowoff + 4) = make_float4(acc[i][4] * rz, acc[i][5] * rz, acc[i][6] * rz, acc[i][7] * rz);
    }
}

extern "C" void kernel_launch(void* const* d_in, const int* in_sizes, int n_in,
                              void* d_out, int out_size, void* d_ws, size_t ws_size,
                              hipStream_t stream) {
    const float* Q    = (const float*)d_in[0];
    const float* K    = (const float*)d_in[1];
    const float* V    = (const float*)d_in[2];
    const float* mask = (const float*)d_in[3];
    float* out = (float*)d_out;

    float* partials = (float*)d_ws;                           // 64*8*4160 floats ≈ 8.5 MB
    float* kvf = partials + (long)NHEAD * NCHUNK * PHEAD;     // 64*4160 floats ≈ 1.1 MB

    pass1_kv<<<NHEAD * NCHUNK, 1024, 0, stream>>>(K, V, mask, partials);
    reduce_kv<<<NHEAD * 4, 256, 0, stream>>>(partials, kvf);
    pass2_out<<<NHEAD * 16, 256, 0, stream>>>(Q, kvf, out);
}